// Round 4
// baseline (1115.519 us; speedup 1.0000x reference)
//
#include <hip/hip_runtime.h>
#include <hip/hip_bf16.h>
#include <math.h>

#define N_NODES 50000
#define N_EDGES 800000
#define GK 256  // K dim of the 256-wide MFMA GEMMs

typedef unsigned short US;
typedef __attribute__((ext_vector_type(8))) short short8;
typedef __attribute__((ext_vector_type(4))) float floatx4;

static __device__ __forceinline__ float bflo(unsigned int u) {
  union { unsigned int i; float f; } c; c.i = u << 16; return c.f;
}
static __device__ __forceinline__ float bfhi(unsigned int u) {
  union { unsigned int i; float f; } c; c.i = u & 0xffff0000u; return c.f;
}
static __device__ __forceinline__ float bf2f(US u) {
  union { unsigned int i; float f; } c; c.i = ((unsigned int)u) << 16; return c.f;
}
static __device__ __forceinline__ US f2bf(float f) {  // round-to-nearest-even
  union { float f; unsigned int i; } c; c.f = f;
  unsigned int x = c.i;
  return (US)((x + 0x7fffu + ((x >> 16) & 1u)) >> 16);
}

// ----------------- preprocessing: degree + CSR build -----------------

__global__ void count_kernel(const int* __restrict__ col, int* __restrict__ cnt, int E) {
  int e = blockIdx.x * blockDim.x + threadIdx.x;
  if (e < E) atomicAdd(&cnt[col[e]], 1);
}

__global__ void dinv_kernel(const int* __restrict__ cnt, float* __restrict__ dinv, int n) {
  int j = blockIdx.x * blockDim.x + threadIdx.x;
  if (j < n) dinv[j] = 1.0f / sqrtf((float)(cnt[j] + 1));  // +1 self-loop
}

__global__ void scan_block_kernel(const int* __restrict__ in, int* __restrict__ out,
                                  int* __restrict__ bsums, int n) {
  __shared__ int s[256];
  int gid = blockIdx.x * 256 + threadIdx.x;
  int v = (gid < n) ? in[gid] : 0;
  s[threadIdx.x] = v;
  __syncthreads();
  for (int off = 1; off < 256; off <<= 1) {
    int t = (threadIdx.x >= off) ? s[threadIdx.x - off] : 0;
    __syncthreads();
    s[threadIdx.x] += t;
    __syncthreads();
  }
  if (gid < n) out[gid] = s[threadIdx.x] - v;  // exclusive
  if (threadIdx.x == 255) bsums[blockIdx.x] = s[255];
}

__global__ void scan_top_kernel(int* __restrict__ bsums, int n) {
  __shared__ int s[256];
  int v = (threadIdx.x < n) ? bsums[threadIdx.x] : 0;
  s[threadIdx.x] = v;
  __syncthreads();
  for (int off = 1; off < 256; off <<= 1) {
    int t = (threadIdx.x >= off) ? s[threadIdx.x - off] : 0;
    __syncthreads();
    s[threadIdx.x] += t;
    __syncthreads();
  }
  if (threadIdx.x < n) bsums[threadIdx.x] = s[threadIdx.x] - v;
}

__global__ void scan_add_kernel(int* __restrict__ row_ptr, int* __restrict__ fill,
                                const int* __restrict__ bsums, int n) {
  int gid = blockIdx.x * 256 + threadIdx.x;
  if (gid < n) {
    int v = row_ptr[gid] + bsums[blockIdx.x];
    row_ptr[gid] = v;
    fill[gid] = v;
  }
}

// packs (src, dinv[src]) so the agg loop has no dependent gather
__global__ void fill_kernel(const int* __restrict__ row, const int* __restrict__ col,
                            int* __restrict__ fill, int2* __restrict__ srcs2,
                            const float* __restrict__ dinv, int E) {
  int e = blockIdx.x * blockDim.x + threadIdx.x;
  if (e < E) {
    int d = col[e];
    int r = row[e];
    int pos = atomicAdd(&fill[d], 1);
    srcs2[pos] = make_int2(r, __float_as_int(dinv[r]));
  }
}

// ----------------- dtype conversion -----------------

__global__ void cvt_x_kernel(const float* __restrict__ x, US* __restrict__ xb, int n4) {
  int idx = blockIdx.x * 256 + threadIdx.x;
  if (idx < n4) {
    float4 v = *(const float4*)(x + (size_t)idx * 4);
    US o[4] = { f2bf(v.x), f2bf(v.y), f2bf(v.z), f2bf(v.w) };
    *(ushort4*)(xb + (size_t)idx * 4) = *(ushort4*)o;
  }
}

// W [K][Nc] fp32 -> Wt [Nc][K] bf16 (transposed so B-fragments are k-contiguous)
__global__ void cvt_w_kernel(const float* __restrict__ W, US* __restrict__ Wt, int K, int Nc) {
  int idx = blockIdx.x * 256 + threadIdx.x;
  if (idx < K * Nc) {
    int k = idx / Nc, n = idx % Nc;
    Wt[(size_t)n * K + k] = f2bf(W[idx]);
  }
}

// ----------------- bf16 MFMA GEMM: C = A[M,256] @ Wt[Nc,256]^T -----------------
// 128x128 tile, 4 waves (2x2 of 64x64), 4x4 16x16x32 fragments per wave, BK=32.
// SLICED epilogue writes tS[slice=col>>5][m][col&31] (XCD-shardable layout).

template <int BN_VALID, bool SLICED>
__global__ __launch_bounds__(256) void gemm_bf16_kernel(
    const US* __restrict__ A, const US* __restrict__ Wt,
    US* __restrict__ C, int M, int Nc) {
  constexpr int LDA = 40;  // 32 + 8 pad
  __shared__ __align__(16) US As[128 * LDA];
  __shared__ __align__(16) US Bs[128 * LDA];
  int tid = threadIdx.x;
  int bm = blockIdx.x * 128;
  int bn = blockIdx.y * 128;
  int lane = tid & 63;
  int w = tid >> 6;
  int wr = (w & 1) * 64, wc = (w >> 1) * 64;
  int lm = lane & 15, lk = lane >> 4;

  floatx4 zero = {0.f, 0.f, 0.f, 0.f};
  floatx4 acc[4][4];
#pragma unroll
  for (int i = 0; i < 4; ++i)
#pragma unroll
    for (int j = 0; j < 4; ++j) acc[i][j] = zero;

  for (int k0 = 0; k0 < GK; k0 += 32) {
#pragma unroll
    for (int it = 0; it < 2; ++it) {
      int idx = tid + it * 256;
      int r = idx >> 2;          // 0..127
      int kc = (idx & 3) * 8;    // bf16 elem offset 0,8,16,24
      uint4 va = {0, 0, 0, 0};
      int gr = bm + r;
      if (gr < M) va = *(const uint4*)(A + (size_t)gr * GK + k0 + kc);
      *(uint4*)&As[r * LDA + kc] = va;
      uint4 vb = {0, 0, 0, 0};
      if (BN_VALID == 128 || r < BN_VALID)
        vb = *(const uint4*)(Wt + (size_t)(bn + r) * GK + k0 + kc);
      *(uint4*)&Bs[r * LDA + kc] = vb;
    }
    __syncthreads();
    short8 af[4], bfr[4];
#pragma unroll
    for (int i = 0; i < 4; ++i)
      af[i] = *(const short8*)&As[(wr + i * 16 + lm) * LDA + lk * 8];
#pragma unroll
    for (int j = 0; j < 4; ++j)
      bfr[j] = *(const short8*)&Bs[(wc + j * 16 + lm) * LDA + lk * 8];
#pragma unroll
    for (int i = 0; i < 4; ++i)
#pragma unroll
      for (int j = 0; j < 4; ++j)
        acc[i][j] = __builtin_amdgcn_mfma_f32_16x16x32_bf16(af[i], bfr[j], acc[i][j], 0, 0, 0);
    __syncthreads();
  }

  // C/D layout: col = lane&15, row = (lane>>4)*4 + reg
#pragma unroll
  for (int i = 0; i < 4; ++i)
#pragma unroll
    for (int j = 0; j < 4; ++j) {
      int col = bn + wc + j * 16 + lm;
#pragma unroll
      for (int r = 0; r < 4; ++r) {
        int m = bm + wr + i * 16 + lk * 4 + r;
        if (m < M) {
          if (SLICED) {
            C[(size_t)(col >> 5) * ((size_t)N_NODES * 32) + (size_t)m * 32 + (col & 31)]
                = f2bf(acc[i][j][r]);
          } else if (col < Nc) {
            C[(size_t)m * Nc + col] = f2bf(acc[i][j][r]);
          }
        }
      }
    }
}

// ----------------- XCD-sliced pull aggregation (D=256) -----------------
// tS layout: [slice][node][32] bf16; slice = blockIdx&7 -> pins each 3.2 MB
// slice to one XCD's L2 (round-robin heuristic). 4 lane-groups of 16 process
// 4 edges in parallel, unroll x2; shfl_xor(16/32) reduces across groups.

template <bool RELU>
__global__ __launch_bounds__(256) void agg256_sliced_kernel(
    const US* __restrict__ tS, US* __restrict__ out,
    const int* __restrict__ row_ptr, const int* __restrict__ cnt,
    const int2* __restrict__ srcs2, const float* __restrict__ dinv,
    const float* __restrict__ bias) {
  int slice = blockIdx.x & 7;
  int nb = blockIdx.x >> 3;
  int wv = threadIdx.x >> 6;
  int lane = threadIdx.x & 63;
  int g = lane >> 4, l = lane & 15;
  const US* ts = tS + (size_t)slice * ((size_t)N_NODES * 32);
  int cbase = slice * 32 + l * 2;
  float b0 = bias[cbase], b1 = bias[cbase + 1];
  int j0 = nb * 32 + wv * 8;
  for (int k = 0; k < 8; ++k) {
    int j = j0 + k;
    if (j >= N_NODES) return;  // uniform across wave
    int start = row_ptr[j];
    int n = cnt[j];
    float a0 = 0.f, a1 = 0.f;
    for (int i = 0; i < n; i += 8) {
      int i0 = i + g, i1 = i + 4 + g;
      int idx0 = start + (i0 < n ? i0 : 0);
      int idx1 = start + (i1 < n ? i1 : 0);
      int2 e0 = srcs2[idx0];
      int2 e1 = srcs2[idx1];
      float w0 = (i0 < n) ? __int_as_float(e0.y) : 0.f;
      float w1 = (i1 < n) ? __int_as_float(e1.y) : 0.f;
      unsigned int v0 = *(const unsigned int*)(ts + (size_t)e0.x * 32 + l * 2);
      unsigned int v1 = *(const unsigned int*)(ts + (size_t)e1.x * 32 + l * 2);
      a0 += bflo(v0) * w0; a1 += bfhi(v0) * w0;
      a0 += bflo(v1) * w1; a1 += bfhi(v1) * w1;
    }
    a0 += __shfl_xor(a0, 16); a0 += __shfl_xor(a0, 32);
    a1 += __shfl_xor(a1, 16); a1 += __shfl_xor(a1, 32);
    float dj = dinv[j];
    unsigned int vj = *(const unsigned int*)(ts + (size_t)j * 32 + l * 2);
    float r0 = (a0 + bflo(vj) * dj) * dj + b0;
    float r1 = (a1 + bfhi(vj) * dj) * dj + b1;
    if (RELU) { r0 = fmaxf(r0, 0.f); r1 = fmaxf(r1, 0.f); }
    if (g == 0) {
      unsigned int o = ((unsigned int)f2bf(r1) << 16) | f2bf(r0);
      *(unsigned int*)(out + (size_t)j * 256 + cbase) = o;
    }
  }
}

// D=64 variant: bf16 row-major in, bf16 out (feeds final MFMA layer), no relu
__global__ __launch_bounds__(64) void agg64_kernel(
    const US* __restrict__ t, US* __restrict__ out,
    const int* __restrict__ row_ptr, const int* __restrict__ cnt,
    const int2* __restrict__ srcs2, const float* __restrict__ dinv,
    const float* __restrict__ bias) {
  int j = blockIdx.x;
  int lane = threadIdx.x;
  int start = row_ptr[j];
  int n = cnt[j];
  float acc = 0.f;
  int i = 0;
  for (; i + 3 < n; i += 4) {
    int2 e0 = srcs2[start + i + 0];
    int2 e1 = srcs2[start + i + 1];
    int2 e2 = srcs2[start + i + 2];
    int2 e3 = srcs2[start + i + 3];
    acc += bf2f(t[(size_t)e0.x * 64 + lane]) * __int_as_float(e0.y);
    acc += bf2f(t[(size_t)e1.x * 64 + lane]) * __int_as_float(e1.y);
    acc += bf2f(t[(size_t)e2.x * 64 + lane]) * __int_as_float(e2.y);
    acc += bf2f(t[(size_t)e3.x * 64 + lane]) * __int_as_float(e3.y);
  }
  for (; i < n; ++i) {
    int2 e = srcs2[start + i];
    acc += bf2f(t[(size_t)e.x * 64 + lane]) * __int_as_float(e.y);
  }
  float dj = dinv[j];
  float r = (acc + bf2f(t[(size_t)j * 64 + lane]) * dj) * dj + bias[lane];
  out[(size_t)j * 64 + lane] = f2bf(r);
}

// ----------------- final dense: sigmoid(H[N,64] @ W4t^T + b4), MFMA -----------------

__global__ __launch_bounds__(256) void final_mfma_kernel(
    const US* __restrict__ H, const US* __restrict__ W4t,
    const float* __restrict__ b4, float* __restrict__ out, int M) {
  int wv = threadIdx.x >> 6, lane = threadIdx.x & 63;
  int m0 = blockIdx.x * 64 + wv * 16;
  if (m0 >= M) return;
  int lm = lane & 15, lk = lane >> 4;

  floatx4 zero = {0.f, 0.f, 0.f, 0.f};
  floatx4 acc[4] = {zero, zero, zero, zero};
#pragma unroll
  for (int ks = 0; ks < 2; ++ks) {
    short8 af = *(const short8*)&H[(size_t)(m0 + lm) * 64 + ks * 32 + lk * 8];
#pragma unroll
    for (int jt = 0; jt < 4; ++jt) {
      short8 bf = *(const short8*)&W4t[(size_t)(jt * 16 + lm) * 64 + ks * 32 + lk * 8];
      acc[jt] = __builtin_amdgcn_mfma_f32_16x16x32_bf16(af, bf, acc[jt], 0, 0, 0);
    }
  }
#pragma unroll
  for (int jt = 0; jt < 4; ++jt) {
    int col = jt * 16 + lm;
    float bv = b4[col];
#pragma unroll
    for (int r = 0; r < 4; ++r) {
      int m = m0 + lk * 4 + r;
      float v = acc[jt][r] + bv;
      out[(size_t)m * 64 + col] = 1.0f / (1.0f + expf(-v));
    }
  }
}

// ----------------- driver -----------------

extern "C" void kernel_launch(void* const* d_in, const int* in_sizes, int n_in,
                              void* d_out, int out_size, void* d_ws, size_t ws_size,
                              hipStream_t stream) {
  const float* x  = (const float*)d_in[0];
  const int* ei   = (const int*)d_in[1];
  const float* W1 = (const float*)d_in[2];
  const float* b1 = (const float*)d_in[3];
  const float* W2 = (const float*)d_in[4];
  const float* b2 = (const float*)d_in[5];
  const float* W3 = (const float*)d_in[6];
  const float* b3 = (const float*)d_in[7];
  const float* W4 = (const float*)d_in[8];
  const float* b4 = (const float*)d_in[9];
  float* outp = (float*)d_out;

  const int N = N_NODES, E = N_EDGES;
  const int* row = ei;
  const int* col = ei + E;

  // workspace layout (~72 MB)
  US* Ab = (US*)d_ws;                         // [N,256] row-major ping
  US* tS = Ab + (size_t)N * 256;              // [8][N][32] sliced pong
  US* B64 = tS + (size_t)N * 256;             // [N,64] row-major (layer-6 GEMM out)
  US* Hfin = B64 + (size_t)N * 64;            // [N,64] (final GEMM in)
  float* dinv = (float*)(Hfin + (size_t)N * 64);
  int* cnt = (int*)(dinv + N);
  int* row_ptr = cnt + N;
  int* fill = row_ptr + N;
  int* bsums = fill + N;                      // [256]
  int2* srcs2 = (int2*)(bsums + 256);         // [E] (src, dinv[src])
  US* Wt1 = (US*)(srcs2 + E);                 // [256,256] bf16 transposed
  US* Wt2 = Wt1 + 256 * 256;
  US* Wt3 = Wt2 + 256 * 256;                  // [64,256]
  US* Wt4 = Wt3 + 64 * 256;                   // [64,64]

  hipMemsetAsync(cnt, 0, N * sizeof(int), stream);
  count_kernel<<<(E + 255) / 256, 256, 0, stream>>>(col, cnt, E);
  dinv_kernel<<<(N + 255) / 256, 256, 0, stream>>>(cnt, dinv, N);
  int nblk = (N + 255) / 256;
  scan_block_kernel<<<nblk, 256, 0, stream>>>(cnt, row_ptr, bsums, N);
  scan_top_kernel<<<1, 256, 0, stream>>>(bsums, nblk);
  scan_add_kernel<<<nblk, 256, 0, stream>>>(row_ptr, fill, bsums, N);
  fill_kernel<<<(E + 255) / 256, 256, 0, stream>>>(row, col, fill, srcs2, dinv, E);

  cvt_x_kernel<<<(N * 256 / 4 + 255) / 256, 256, 0, stream>>>(x, Ab, N * 256 / 4);
  cvt_w_kernel<<<(256 * 256 + 255) / 256, 256, 0, stream>>>(W1, Wt1, 256, 256);
  cvt_w_kernel<<<(256 * 256 + 255) / 256, 256, 0, stream>>>(W2, Wt2, 256, 256);
  cvt_w_kernel<<<(256 * 64 + 255) / 256, 256, 0, stream>>>(W3, Wt3, 256, 64);
  cvt_w_kernel<<<(64 * 64 + 255) / 256, 256, 0, stream>>>(W4, Wt4, 64, 64);

  dim3 g2((N + 127) / 128, 2);
  dim3 g1((N + 127) / 128, 1);
  int gagg = 8 * ((N + 31) / 32);  // slice-interleaved: blockIdx%8 = slice

  gemm_bf16_kernel<128, true><<<g2, 256, 0, stream>>>(Ab, Wt1, tS, N, 256);
  agg256_sliced_kernel<true><<<gagg, 256, 0, stream>>>(tS, Ab, row_ptr, cnt, srcs2, dinv, b1);
  for (int l = 0; l < 4; ++l) {
    gemm_bf16_kernel<128, true><<<g2, 256, 0, stream>>>(Ab, Wt2, tS, N, 256);
    agg256_sliced_kernel<true><<<gagg, 256, 0, stream>>>(tS, Ab, row_ptr, cnt, srcs2, dinv, b2);
  }
  gemm_bf16_kernel<64, false><<<g1, 256, 0, stream>>>(Ab, Wt3, B64, N, 64);
  agg64_kernel<<<N, 64, 0, stream>>>(B64, Hfin, row_ptr, cnt, srcs2, dinv, b3);
  final_mfma_kernel<<<(N + 63) / 64, 256, 0, stream>>>(Hfin, Wt4, b4, outp, N);
}

// Round 5
// 642.015 us; speedup vs baseline: 1.7375x; 1.7375x over previous
//
#include <hip/hip_runtime.h>
#include <hip/hip_bf16.h>
#include <math.h>

#define N_NODES 50000
#define N_EDGES 800000
#define GK 256  // K dim of the 256-wide MFMA GEMMs

typedef unsigned short US;
typedef __attribute__((ext_vector_type(8))) short short8;
typedef __attribute__((ext_vector_type(4))) float floatx4;
typedef __attribute__((address_space(1))) const void* gptr_t;
typedef __attribute__((address_space(3))) void* lptr_t;

static __device__ __forceinline__ float bflo(unsigned int u) {
  union { unsigned int i; float f; } c; c.i = u << 16; return c.f;
}
static __device__ __forceinline__ float bfhi(unsigned int u) {
  union { unsigned int i; float f; } c; c.i = u & 0xffff0000u; return c.f;
}
static __device__ __forceinline__ float bf2f(US u) {
  union { unsigned int i; float f; } c; c.i = ((unsigned int)u) << 16; return c.f;
}
static __device__ __forceinline__ US f2bf(float f) {  // round-to-nearest-even
  union { float f; unsigned int i; } c; c.f = f;
  unsigned int x = c.i;
  return (US)((x + 0x7fffu + ((x >> 16) & 1u)) >> 16);
}

// ----------------- preprocessing: degree + CSR build -----------------

__global__ void count_kernel(const int* __restrict__ col, int* __restrict__ cnt, int E) {
  int e = blockIdx.x * blockDim.x + threadIdx.x;
  if (e < E) atomicAdd(&cnt[col[e]], 1);
}

__global__ void dinv_kernel(const int* __restrict__ cnt, float* __restrict__ dinv, int n) {
  int j = blockIdx.x * blockDim.x + threadIdx.x;
  if (j < n) dinv[j] = 1.0f / sqrtf((float)(cnt[j] + 1));  // +1 self-loop
}

__global__ void scan_block_kernel(const int* __restrict__ in, int* __restrict__ out,
                                  int* __restrict__ bsums, int n) {
  __shared__ int s[256];
  int gid = blockIdx.x * 256 + threadIdx.x;
  int v = (gid < n) ? in[gid] : 0;
  s[threadIdx.x] = v;
  __syncthreads();
  for (int off = 1; off < 256; off <<= 1) {
    int t = (threadIdx.x >= off) ? s[threadIdx.x - off] : 0;
    __syncthreads();
    s[threadIdx.x] += t;
    __syncthreads();
  }
  if (gid < n) out[gid] = s[threadIdx.x] - v;  // exclusive
  if (threadIdx.x == 255) bsums[blockIdx.x] = s[255];
}

__global__ void scan_top_kernel(int* __restrict__ bsums, int n) {
  __shared__ int s[256];
  int v = (threadIdx.x < n) ? bsums[threadIdx.x] : 0;
  s[threadIdx.x] = v;
  __syncthreads();
  for (int off = 1; off < 256; off <<= 1) {
    int t = (threadIdx.x >= off) ? s[threadIdx.x - off] : 0;
    __syncthreads();
    s[threadIdx.x] += t;
    __syncthreads();
  }
  if (threadIdx.x < n) bsums[threadIdx.x] = s[threadIdx.x] - v;
}

__global__ void scan_add_kernel(int* __restrict__ row_ptr, int* __restrict__ fill,
                                const int* __restrict__ bsums, int n) {
  int gid = blockIdx.x * 256 + threadIdx.x;
  if (gid < n) {
    int v = row_ptr[gid] + bsums[blockIdx.x];
    row_ptr[gid] = v;
    fill[gid] = v;
  }
}

// packs (src, dinv[src]) so the agg loop has no dependent gather
__global__ void fill_kernel(const int* __restrict__ row, const int* __restrict__ col,
                            int* __restrict__ fill, int2* __restrict__ srcs2,
                            const float* __restrict__ dinv, int E) {
  int e = blockIdx.x * blockDim.x + threadIdx.x;
  if (e < E) {
    int d = col[e];
    int r = row[e];
    int pos = atomicAdd(&fill[d], 1);
    srcs2[pos] = make_int2(r, __float_as_int(dinv[r]));
  }
}

// ----------------- dtype conversion -----------------

__global__ void cvt_x_kernel(const float* __restrict__ x, US* __restrict__ xb, int n4) {
  int idx = blockIdx.x * 256 + threadIdx.x;
  if (idx < n4) {
    float4 v = *(const float4*)(x + (size_t)idx * 4);
    US o[4] = { f2bf(v.x), f2bf(v.y), f2bf(v.z), f2bf(v.w) };
    *(ushort4*)(xb + (size_t)idx * 4) = *(ushort4*)o;
  }
}

// W [K][Nc] fp32 -> Wt [Nc][K] bf16 (transposed so B-fragments are k-contiguous)
__global__ void cvt_w_kernel(const float* __restrict__ W, US* __restrict__ Wt, int K, int Nc) {
  int idx = blockIdx.x * 256 + threadIdx.x;
  if (idx < K * Nc) {
    int k = idx / Nc, n = idx % Nc;
    Wt[(size_t)n * K + k] = f2bf(W[idx]);
  }
}

// ----------------- bf16 MFMA GEMM: C = A[M,256] @ Wt[Nc,256]^T -----------------
// 128x128 tile, 4 waves (2x2 of 64x64), 4x4 16x16x32 fragments, BK=64.
// m97 recipe: global_load_lds width=16 staging into unpadded XOR-swizzled LDS.
// LDS layout: tile[row][chunk c] (16B chunks, 8/row) holds global chunk
// c ^ (row&7)  -> staging is lane-contiguous (base + lane*16) AND fragment
// ds_read_b128 lands 2-way bank aliasing (free, m136).

template <int BN_VALID>
__global__ __launch_bounds__(256) void gemm_bf16_kernel(
    const US* __restrict__ A, const US* __restrict__ Wt,
    US* __restrict__ C, int M, int Nc) {
  __shared__ __align__(16) US As[128 * 64];
  __shared__ __align__(16) US Bs[128 * 64];
  int tid = threadIdx.x;
  int bm = blockIdx.x * 128;
  int bn = blockIdx.y * 128;
  int lane = tid & 63;
  int w = tid >> 6;
  int wr = (w & 1) * 64, wc = (w >> 1) * 64;
  int lm = lane & 15, lk = lane >> 4;
  int lr = lane >> 3;        // staging: local row 0..7 within 8-row chunk
  int lc = lane & 7;         // staging: stored 16B-chunk col 0..7
  int gc = lc ^ lr;          // staging: global 16B-chunk col (XOR swizzle)

  floatx4 zero = {0.f, 0.f, 0.f, 0.f};
  floatx4 acc[4][4];
#pragma unroll
  for (int i = 0; i < 4; ++i)
#pragma unroll
    for (int j = 0; j < 4; ++j) acc[i][j] = zero;

  for (int k0 = 0; k0 < GK; k0 += 64) {
    // stage A and B tiles: per wave 4 chunks of 8 rows x 128B each
#pragma unroll
    for (int i = 0; i < 4; ++i) {
      int rbase = (w * 4 + i) * 8;         // tile row base 0..120
      int r = rbase + lr;
      int gr = bm + r;
      const US* ga = A + (size_t)gr * GK + k0 + gc * 8;
      lptr_t la = (lptr_t)(void*)&As[rbase * 64];   // wave-uniform base; lane lands at +lane*16
      if (gr < M)
        __builtin_amdgcn_global_load_lds((gptr_t)(const void*)ga, la, 16, 0, 0);
      const US* gb = Wt + (size_t)(bn + r) * GK + k0 + gc * 8;
      lptr_t lb = (lptr_t)(void*)&Bs[rbase * 64];
      __builtin_amdgcn_global_load_lds((gptr_t)(const void*)gb, lb, 16, 0, 0);
    }
    __syncthreads();

#pragma unroll
    for (int s = 0; s < 2; ++s) {   // two k=32 sub-steps per staged BK=64
      short8 af[4], bfr[4];
#pragma unroll
      for (int i = 0; i < 4; ++i) {
        int row = wr + i * 16 + lm;
        int c = (s * 4 + lk) ^ (row & 7);
        af[i] = *(const short8*)&As[row * 64 + c * 8];
      }
#pragma unroll
      for (int j = 0; j < 4; ++j) {
        int row = wc + j * 16 + lm;
        int c = (s * 4 + lk) ^ (row & 7);
        bfr[j] = *(const short8*)&Bs[row * 64 + c * 8];
      }
#pragma unroll
      for (int i = 0; i < 4; ++i)
#pragma unroll
        for (int j = 0; j < 4; ++j)
          acc[i][j] = __builtin_amdgcn_mfma_f32_16x16x32_bf16(af[i], bfr[j], acc[i][j], 0, 0, 0);
    }
    __syncthreads();
  }

  // C/D layout: col = lane&15, row = (lane>>4)*4 + reg
#pragma unroll
  for (int i = 0; i < 4; ++i)
#pragma unroll
    for (int j = 0; j < 4; ++j) {
      int col = bn + wc + j * 16 + lm;
#pragma unroll
      for (int r = 0; r < 4; ++r) {
        int m = bm + wr + i * 16 + lk * 4 + r;
        if (m < M && (BN_VALID == 128 || col < Nc))
          C[(size_t)m * Nc + col] = f2bf(acc[i][j][r]);
      }
    }
}

// ----------------- pull aggregation (R3 structure): one wave per node -----------------
// out[j] = relu?( dinv[j]*(sum_src t[s]*dinv[s] + t[j]*dinv[j]) + bias )
// 8B/lane row loads, unroll-4, packed (src,dinv) stream.

template <bool RELU>
__global__ __launch_bounds__(64) void agg256_kernel(
    const US* __restrict__ t, US* __restrict__ out,
    const int* __restrict__ row_ptr, const int* __restrict__ cnt,
    const int2* __restrict__ srcs2, const float* __restrict__ dinv,
    const float* __restrict__ bias) {
  int j = blockIdx.x;
  int lane = threadIdx.x;
  int base = lane * 4;
  int start = row_ptr[j];
  int n = cnt[j];
  float a0 = 0.f, a1 = 0.f, a2 = 0.f, a3 = 0.f;
  int i = 0;
  for (; i + 3 < n; i += 4) {
    int2 e0 = srcs2[start + i + 0];
    int2 e1 = srcs2[start + i + 1];
    int2 e2 = srcs2[start + i + 2];
    int2 e3 = srcs2[start + i + 3];
    float w0 = __int_as_float(e0.y), w1 = __int_as_float(e1.y);
    float w2 = __int_as_float(e2.y), w3 = __int_as_float(e3.y);
    uint2 v0 = *(const uint2*)(t + (size_t)e0.x * 256 + base);
    uint2 v1 = *(const uint2*)(t + (size_t)e1.x * 256 + base);
    uint2 v2 = *(const uint2*)(t + (size_t)e2.x * 256 + base);
    uint2 v3 = *(const uint2*)(t + (size_t)e3.x * 256 + base);
    a0 += bflo(v0.x) * w0; a1 += bfhi(v0.x) * w0;
    a2 += bflo(v0.y) * w0; a3 += bfhi(v0.y) * w0;
    a0 += bflo(v1.x) * w1; a1 += bfhi(v1.x) * w1;
    a2 += bflo(v1.y) * w1; a3 += bfhi(v1.y) * w1;
    a0 += bflo(v2.x) * w2; a1 += bfhi(v2.x) * w2;
    a2 += bflo(v2.y) * w2; a3 += bfhi(v2.y) * w2;
    a0 += bflo(v3.x) * w3; a1 += bfhi(v3.x) * w3;
    a2 += bflo(v3.y) * w3; a3 += bfhi(v3.y) * w3;
  }
  for (; i < n; ++i) {
    int2 e = srcs2[start + i];
    float w0 = __int_as_float(e.y);
    uint2 v0 = *(const uint2*)(t + (size_t)e.x * 256 + base);
    a0 += bflo(v0.x) * w0; a1 += bfhi(v0.x) * w0;
    a2 += bflo(v0.y) * w0; a3 += bfhi(v0.y) * w0;
  }
  float dj = dinv[j];
  uint2 vj = *(const uint2*)(t + (size_t)j * 256 + base);
  float r0 = (a0 + bflo(vj.x) * dj) * dj + bias[base + 0];
  float r1 = (a1 + bfhi(vj.x) * dj) * dj + bias[base + 1];
  float r2 = (a2 + bflo(vj.y) * dj) * dj + bias[base + 2];
  float r3 = (a3 + bfhi(vj.y) * dj) * dj + bias[base + 3];
  if (RELU) {
    r0 = fmaxf(r0, 0.f); r1 = fmaxf(r1, 0.f);
    r2 = fmaxf(r2, 0.f); r3 = fmaxf(r3, 0.f);
  }
  unsigned int o0 = ((unsigned int)f2bf(r1) << 16) | f2bf(r0);
  unsigned int o1 = ((unsigned int)f2bf(r3) << 16) | f2bf(r2);
  *(uint2*)(out + (size_t)j * 256 + base) = make_uint2(o0, o1);
}

// D=64 variant: bf16 in, bf16 out (feeds final MFMA layer), no relu
__global__ __launch_bounds__(64) void agg64_kernel(
    const US* __restrict__ t, US* __restrict__ out,
    const int* __restrict__ row_ptr, const int* __restrict__ cnt,
    const int2* __restrict__ srcs2, const float* __restrict__ dinv,
    const float* __restrict__ bias) {
  int j = blockIdx.x;
  int lane = threadIdx.x;
  int start = row_ptr[j];
  int n = cnt[j];
  float acc = 0.f;
  int i = 0;
  for (; i + 3 < n; i += 4) {
    int2 e0 = srcs2[start + i + 0];
    int2 e1 = srcs2[start + i + 1];
    int2 e2 = srcs2[start + i + 2];
    int2 e3 = srcs2[start + i + 3];
    acc += bf2f(t[(size_t)e0.x * 64 + lane]) * __int_as_float(e0.y);
    acc += bf2f(t[(size_t)e1.x * 64 + lane]) * __int_as_float(e1.y);
    acc += bf2f(t[(size_t)e2.x * 64 + lane]) * __int_as_float(e2.y);
    acc += bf2f(t[(size_t)e3.x * 64 + lane]) * __int_as_float(e3.y);
  }
  for (; i < n; ++i) {
    int2 e = srcs2[start + i];
    acc += bf2f(t[(size_t)e.x * 64 + lane]) * __int_as_float(e.y);
  }
  float dj = dinv[j];
  float r = (acc + bf2f(t[(size_t)j * 64 + lane]) * dj) * dj + bias[lane];
  out[(size_t)j * 64 + lane] = f2bf(r);
}

// ----------------- final dense: sigmoid(H[N,64] @ W4t^T + b4), MFMA -----------------

__global__ __launch_bounds__(256) void final_mfma_kernel(
    const US* __restrict__ H, const US* __restrict__ W4t,
    const float* __restrict__ b4, float* __restrict__ out, int M) {
  int wv = threadIdx.x >> 6, lane = threadIdx.x & 63;
  int m0 = blockIdx.x * 64 + wv * 16;
  if (m0 >= M) return;
  int lm = lane & 15, lk = lane >> 4;

  floatx4 zero = {0.f, 0.f, 0.f, 0.f};
  floatx4 acc[4] = {zero, zero, zero, zero};
#pragma unroll
  for (int ks = 0; ks < 2; ++ks) {
    short8 af = *(const short8*)&H[(size_t)(m0 + lm) * 64 + ks * 32 + lk * 8];
#pragma unroll
    for (int jt = 0; jt < 4; ++jt) {
      short8 bf = *(const short8*)&W4t[(size_t)(jt * 16 + lm) * 64 + ks * 32 + lk * 8];
      acc[jt] = __builtin_amdgcn_mfma_f32_16x16x32_bf16(af, bf, acc[jt], 0, 0, 0);
    }
  }
#pragma unroll
  for (int jt = 0; jt < 4; ++jt) {
    int col = jt * 16 + lm;
    float bv = b4[col];
#pragma unroll
    for (int r = 0; r < 4; ++r) {
      int m = m0 + lk * 4 + r;
      float v = acc[jt][r] + bv;
      out[(size_t)m * 64 + col] = 1.0f / (1.0f + expf(-v));
    }
  }
}

// ----------------- driver -----------------

extern "C" void kernel_launch(void* const* d_in, const int* in_sizes, int n_in,
                              void* d_out, int out_size, void* d_ws, size_t ws_size,
                              hipStream_t stream) {
  const float* x  = (const float*)d_in[0];
  const int* ei   = (const int*)d_in[1];
  const float* W1 = (const float*)d_in[2];
  const float* b1 = (const float*)d_in[3];
  const float* W2 = (const float*)d_in[4];
  const float* b2 = (const float*)d_in[5];
  const float* W3 = (const float*)d_in[6];
  const float* b3 = (const float*)d_in[7];
  const float* W4 = (const float*)d_in[8];
  const float* b4 = (const float*)d_in[9];
  float* outp = (float*)d_out;

  const int N = N_NODES, E = N_EDGES;
  const int* row = ei;
  const int* col = ei + E;

  // workspace layout (~72 MB)
  US* Ab = (US*)d_ws;                         // [N,256] bf16 ping
  US* Bb = Ab + (size_t)N * 256;              // [N,256] bf16 pong
  US* B64 = Bb + (size_t)N * 256;             // [N,64] (layer-6 GEMM out)
  US* Hfin = B64 + (size_t)N * 64;            // [N,64] (final GEMM in)
  float* dinv = (float*)(Hfin + (size_t)N * 64);
  int* cnt = (int*)(dinv + N);
  int* row_ptr = cnt + N;
  int* fill = row_ptr + N;
  int* bsums = fill + N;                      // [256]
  int2* srcs2 = (int2*)(bsums + 256);         // [E] (src, dinv[src])
  US* Wt1 = (US*)(srcs2 + E);                 // [256,256] bf16 transposed
  US* Wt2 = Wt1 + 256 * 256;
  US* Wt3 = Wt2 + 256 * 256;                  // [64,256]
  US* Wt4 = Wt3 + 64 * 256;                   // [64,64]

  hipMemsetAsync(cnt, 0, N * sizeof(int), stream);
  count_kernel<<<(E + 255) / 256, 256, 0, stream>>>(col, cnt, E);
  dinv_kernel<<<(N + 255) / 256, 256, 0, stream>>>(cnt, dinv, N);
  int nblk = (N + 255) / 256;
  scan_block_kernel<<<nblk, 256, 0, stream>>>(cnt, row_ptr, bsums, N);
  scan_top_kernel<<<1, 256, 0, stream>>>(bsums, nblk);
  scan_add_kernel<<<nblk, 256, 0, stream>>>(row_ptr, fill, bsums, N);
  fill_kernel<<<(E + 255) / 256, 256, 0, stream>>>(row, col, fill, srcs2, dinv, E);

  cvt_x_kernel<<<(N * 256 / 4 + 255) / 256, 256, 0, stream>>>(x, Ab, N * 256 / 4);
  cvt_w_kernel<<<(256 * 256 + 255) / 256, 256, 0, stream>>>(W1, Wt1, 256, 256);
  cvt_w_kernel<<<(256 * 256 + 255) / 256, 256, 0, stream>>>(W2, Wt2, 256, 256);
  cvt_w_kernel<<<(256 * 64 + 255) / 256, 256, 0, stream>>>(W3, Wt3, 256, 64);
  cvt_w_kernel<<<(64 * 64 + 255) / 256, 256, 0, stream>>>(W4, Wt4, 64, 64);

  dim3 g2((N + 127) / 128, 2);
  dim3 g1((N + 127) / 128, 1);

  gemm_bf16_kernel<128><<<g2, 256, 0, stream>>>(Ab, Wt1, Bb, N, 256);
  agg256_kernel<true><<<N, 64, 0, stream>>>(Bb, Ab, row_ptr, cnt, srcs2, dinv, b1);
  for (int l = 0; l < 4; ++l) {
    gemm_bf16_kernel<128><<<g2, 256, 0, stream>>>(Ab, Wt2, Bb, N, 256);
    agg256_kernel<true><<<N, 64, 0, stream>>>(Bb, Ab, row_ptr, cnt, srcs2, dinv, b2);
  }
  gemm_bf16_kernel<64><<<g1, 256, 0, stream>>>(Ab, Wt3, B64, N, 64);
  agg64_kernel<<<N, 64, 0, stream>>>(B64, Hfin, row_ptr, cnt, srcs2, dinv, b3);
  final_mfma_kernel<<<(N + 63) / 64, 256, 0, stream>>>(Hfin, Wt4, b4, outp, N);
}

// Round 6
// 622.770 us; speedup vs baseline: 1.7912x; 1.0309x over previous
//
#include <hip/hip_runtime.h>
#include <hip/hip_bf16.h>
#include <math.h>

#define N_NODES 50000
#define N_EDGES 800000
#define GK 256  // K dim of all big GEMMs

typedef unsigned short US;
typedef __attribute__((ext_vector_type(8))) short short8;
typedef __attribute__((ext_vector_type(4))) float floatx4;
typedef __attribute__((address_space(1))) const void* gptr_t;
typedef __attribute__((address_space(3))) void* lptr_t;

static __device__ __forceinline__ float bflo(unsigned int u) {
  union { unsigned int i; float f; } c; c.i = u << 16; return c.f;
}
static __device__ __forceinline__ float bfhi(unsigned int u) {
  union { unsigned int i; float f; } c; c.i = u & 0xffff0000u; return c.f;
}
static __device__ __forceinline__ float bf2f(US u) {
  union { unsigned int i; float f; } c; c.i = ((unsigned int)u) << 16; return c.f;
}
static __device__ __forceinline__ US f2bf(float f) {  // round-to-nearest-even
  union { float f; unsigned int i; } c; c.f = f;
  unsigned int x = c.i;
  return (US)((x + 0x7fffu + ((x >> 16) & 1u)) >> 16);
}

// ----------------- preprocessing: degree + CSR build -----------------

__global__ void count_kernel(const int* __restrict__ col, int* __restrict__ cnt, int E) {
  int e = blockIdx.x * blockDim.x + threadIdx.x;
  if (e < E) atomicAdd(&cnt[col[e]], 1);
}

// scan_block also emits dinv = 1/sqrt(deg+1) (fuses old dinv_kernel)
__global__ void scan_block_kernel(const int* __restrict__ in, int* __restrict__ out,
                                  int* __restrict__ bsums, float* __restrict__ dinv, int n) {
  __shared__ int s[256];
  int gid = blockIdx.x * 256 + threadIdx.x;
  int v = (gid < n) ? in[gid] : 0;
  if (gid < n) dinv[gid] = 1.0f / sqrtf((float)(v + 1));  // +1 self-loop
  s[threadIdx.x] = v;
  __syncthreads();
  for (int off = 1; off < 256; off <<= 1) {
    int t = (threadIdx.x >= off) ? s[threadIdx.x - off] : 0;
    __syncthreads();
    s[threadIdx.x] += t;
    __syncthreads();
  }
  if (gid < n) out[gid] = s[threadIdx.x] - v;  // exclusive
  if (threadIdx.x == 255) bsums[blockIdx.x] = s[255];
}

__global__ void scan_top_kernel(int* __restrict__ bsums, int n) {
  __shared__ int s[256];
  int v = (threadIdx.x < n) ? bsums[threadIdx.x] : 0;
  s[threadIdx.x] = v;
  __syncthreads();
  for (int off = 1; off < 256; off <<= 1) {
    int t = (threadIdx.x >= off) ? s[threadIdx.x - off] : 0;
    __syncthreads();
    s[threadIdx.x] += t;
    __syncthreads();
  }
  if (threadIdx.x < n) bsums[threadIdx.x] = s[threadIdx.x] - v;
}

__global__ void scan_add_kernel(int* __restrict__ row_ptr, int* __restrict__ fill,
                                const int* __restrict__ bsums, int n) {
  int gid = blockIdx.x * 256 + threadIdx.x;
  if (gid < n) {
    int v = row_ptr[gid] + bsums[blockIdx.x];
    row_ptr[gid] = v;
    fill[gid] = v;
  }
}

// packs (src, dinv[src]) so the agg loop has no dependent gather
__global__ void fill_kernel(const int* __restrict__ row, const int* __restrict__ col,
                            int* __restrict__ fill, int2* __restrict__ srcs2,
                            const float* __restrict__ dinv, int E) {
  int e = blockIdx.x * blockDim.x + threadIdx.x;
  if (e < E) {
    int d = col[e];
    int r = row[e];
    int pos = atomicAdd(&fill[d], 1);
    srcs2[pos] = make_int2(r, __float_as_int(dinv[r]));
  }
}

// ----------------- dtype conversion -----------------

__global__ void cvt_x_kernel(const float* __restrict__ x, US* __restrict__ xb, int n4) {
  int idx = blockIdx.x * 256 + threadIdx.x;
  if (idx < n4) {
    float4 v = *(const float4*)(x + (size_t)idx * 4);
    US o[4] = { f2bf(v.x), f2bf(v.y), f2bf(v.z), f2bf(v.w) };
    *(ushort4*)(xb + (size_t)idx * 4) = *(ushort4*)o;
  }
}

// all four weights fp32 -> bf16 transposed in one launch
__global__ void cvt_w_all_kernel(const float* __restrict__ W1, const float* __restrict__ W2,
                                 const float* __restrict__ W3, const float* __restrict__ W4,
                                 US* __restrict__ Wt1, US* __restrict__ Wt2,
                                 US* __restrict__ Wt3, US* __restrict__ Wt4) {
  int idx = blockIdx.x * 256 + threadIdx.x;
  if (idx < 65536) {                       // W1 [256,256]
    int k = idx >> 8, n = idx & 255;
    Wt1[n * 256 + k] = f2bf(W1[idx]);
  } else if (idx < 131072) {               // W2 [256,256]
    int i = idx - 65536, k = i >> 8, n = i & 255;
    Wt2[n * 256 + k] = f2bf(W2[i]);
  } else if (idx < 147456) {               // W3 [256,64]
    int i = idx - 131072, k = i >> 6, n = i & 63;
    Wt3[n * 256 + k] = f2bf(W3[i]);
  } else if (idx < 151552) {               // W4 [64,64]
    int i = idx - 147456, k = i >> 6, n = i & 63;
    Wt4[n * 64 + k] = f2bf(W4[i]);
  }
}

// ----------------- gemm256: C[M,256] = A[M,256] @ Wt[256,256]^T -----------------
// M-tile 64 per block (A read ONCE), full N=256; 4 waves own 64-col quadrants.
// BK=64, global_load_lds width=16, XOR-swizzled unpadded LDS (2-way alias = free).

__global__ __launch_bounds__(256) void gemm256_kernel(
    const US* __restrict__ A, const US* __restrict__ Wt,
    US* __restrict__ C, int M) {
  __shared__ __align__(16) US As[64 * 64];    // 8 KB
  __shared__ __align__(16) US Bs[256 * 64];   // 32 KB
  int tid = threadIdx.x;
  int bm = blockIdx.x * 64;
  int lane = tid & 63;
  int w = tid >> 6;
  int wc = w * 64;                 // wave's column quadrant
  int lm = lane & 15, lk = lane >> 4;
  int lr = lane >> 3;              // staging: row within 8-row group
  int lc = lane & 7;               // staging: stored 16B-chunk
  int gc = lc ^ lr;                // staging: fetched global chunk (XOR swizzle)

  floatx4 zero = {0.f, 0.f, 0.f, 0.f};
  floatx4 acc[4][4];
#pragma unroll
  for (int i = 0; i < 4; ++i)
#pragma unroll
    for (int j = 0; j < 4; ++j) acc[i][j] = zero;

  for (int k0 = 0; k0 < GK; k0 += 64) {
    // A tile: 64 rows x 128B, 2 issues (4 waves x 8 rows each)
#pragma unroll
    for (int i = 0; i < 2; ++i) {
      int rbase = i * 32 + w * 8;
      int r = rbase + lr;
      const US* ga = A + (size_t)(bm + r) * GK + k0 + gc * 8;
      lptr_t la = (lptr_t)(void*)&As[rbase * 64];
      if (bm + r < M)
        __builtin_amdgcn_global_load_lds((gptr_t)(const void*)ga, la, 16, 0, 0);
    }
    // B tile: 256 rows x 128B, 8 issues
#pragma unroll
    for (int i = 0; i < 8; ++i) {
      int rbase = i * 32 + w * 8;
      int r = rbase + lr;
      const US* gb = Wt + (size_t)r * GK + k0 + gc * 8;
      lptr_t lb = (lptr_t)(void*)&Bs[rbase * 64];
      __builtin_amdgcn_global_load_lds((gptr_t)(const void*)gb, lb, 16, 0, 0);
    }
    __syncthreads();

#pragma unroll
    for (int s = 0; s < 2; ++s) {
      short8 af[4], bfr[4];
#pragma unroll
      for (int i = 0; i < 4; ++i) {
        int row = i * 16 + lm;
        int c = (s * 4 + lk) ^ (row & 7);
        af[i] = *(const short8*)&As[row * 64 + c * 8];
      }
#pragma unroll
      for (int j = 0; j < 4; ++j) {
        int row = wc + j * 16 + lm;
        int c = (s * 4 + lk) ^ (row & 7);
        bfr[j] = *(const short8*)&Bs[row * 64 + c * 8];
      }
#pragma unroll
      for (int i = 0; i < 4; ++i)
#pragma unroll
        for (int j = 0; j < 4; ++j)
          acc[i][j] = __builtin_amdgcn_mfma_f32_16x16x32_bf16(af[i], bfr[j], acc[i][j], 0, 0, 0);
    }
    __syncthreads();
  }

  // C/D layout: col = lane&15, row = (lane>>4)*4 + reg
#pragma unroll
  for (int i = 0; i < 4; ++i)
#pragma unroll
    for (int j = 0; j < 4; ++j) {
      int colg = wc + j * 16 + lm;
#pragma unroll
      for (int r = 0; r < 4; ++r) {
        int m = bm + i * 16 + lk * 4 + r;
        if (m < M) C[(size_t)m * 256 + colg] = f2bf(acc[i][j][r]);
      }
    }
}

// ----------------- gemm64: C[M,64] = A[M,256] @ Wt3[64,256]^T -----------------
// M-tile 128; 4 waves own 32-row strips x all 64 cols; acc 2x4.

__global__ __launch_bounds__(256) void gemm64_kernel(
    const US* __restrict__ A, const US* __restrict__ Wt,
    US* __restrict__ C, int M) {
  __shared__ __align__(16) US As[128 * 64];   // 16 KB
  __shared__ __align__(16) US Bs[64 * 64];    // 8 KB
  int tid = threadIdx.x;
  int bm = blockIdx.x * 128;
  int lane = tid & 63;
  int w = tid >> 6;
  int wr = w * 32;
  int lm = lane & 15, lk = lane >> 4;
  int lr = lane >> 3;
  int lc = lane & 7;
  int gc = lc ^ lr;

  floatx4 zero = {0.f, 0.f, 0.f, 0.f};
  floatx4 acc[2][4];
#pragma unroll
  for (int i = 0; i < 2; ++i)
#pragma unroll
    for (int j = 0; j < 4; ++j) acc[i][j] = zero;

  for (int k0 = 0; k0 < GK; k0 += 64) {
#pragma unroll
    for (int i = 0; i < 4; ++i) {       // A: 128 rows
      int rbase = i * 32 + w * 8;
      int r = rbase + lr;
      const US* ga = A + (size_t)(bm + r) * GK + k0 + gc * 8;
      lptr_t la = (lptr_t)(void*)&As[rbase * 64];
      if (bm + r < M)
        __builtin_amdgcn_global_load_lds((gptr_t)(const void*)ga, la, 16, 0, 0);
    }
#pragma unroll
    for (int i = 0; i < 2; ++i) {       // B: 64 rows
      int rbase = i * 32 + w * 8;
      int r = rbase + lr;
      const US* gb = Wt + (size_t)r * GK + k0 + gc * 8;
      lptr_t lb = (lptr_t)(void*)&Bs[rbase * 64];
      __builtin_amdgcn_global_load_lds((gptr_t)(const void*)gb, lb, 16, 0, 0);
    }
    __syncthreads();

#pragma unroll
    for (int s = 0; s < 2; ++s) {
      short8 af[2], bfr[4];
#pragma unroll
      for (int i = 0; i < 2; ++i) {
        int row = wr + i * 16 + lm;
        int c = (s * 4 + lk) ^ (row & 7);
        af[i] = *(const short8*)&As[row * 64 + c * 8];
      }
#pragma unroll
      for (int j = 0; j < 4; ++j) {
        int row = j * 16 + lm;
        int c = (s * 4 + lk) ^ (row & 7);
        bfr[j] = *(const short8*)&Bs[row * 64 + c * 8];
      }
#pragma unroll
      for (int i = 0; i < 2; ++i)
#pragma unroll
        for (int j = 0; j < 4; ++j)
          acc[i][j] = __builtin_amdgcn_mfma_f32_16x16x32_bf16(af[i], bfr[j], acc[i][j], 0, 0, 0);
    }
    __syncthreads();
  }

#pragma unroll
  for (int i = 0; i < 2; ++i)
#pragma unroll
    for (int j = 0; j < 4; ++j) {
      int colg = j * 16 + lm;
#pragma unroll
      for (int r = 0; r < 4; ++r) {
        int m = bm + wr + i * 16 + lk * 4 + r;
        if (m < M) C[(size_t)m * 64 + colg] = f2bf(acc[i][j][r]);
      }
    }
}

// ----------------- pull aggregation: one wave per node (floored at ~59us) -----------------

template <bool RELU>
__global__ __launch_bounds__(64) void agg256_kernel(
    const US* __restrict__ t, US* __restrict__ out,
    const int* __restrict__ row_ptr, const int* __restrict__ cnt,
    const int2* __restrict__ srcs2, const float* __restrict__ dinv,
    const float* __restrict__ bias) {
  int j = blockIdx.x;
  int lane = threadIdx.x;
  int base = lane * 4;
  int start = row_ptr[j];
  int n = cnt[j];
  float a0 = 0.f, a1 = 0.f, a2 = 0.f, a3 = 0.f;
  int i = 0;
  for (; i + 3 < n; i += 4) {
    int2 e0 = srcs2[start + i + 0];
    int2 e1 = srcs2[start + i + 1];
    int2 e2 = srcs2[start + i + 2];
    int2 e3 = srcs2[start + i + 3];
    float w0 = __int_as_float(e0.y), w1 = __int_as_float(e1.y);
    float w2 = __int_as_float(e2.y), w3 = __int_as_float(e3.y);
    uint2 v0 = *(const uint2*)(t + (size_t)e0.x * 256 + base);
    uint2 v1 = *(const uint2*)(t + (size_t)e1.x * 256 + base);
    uint2 v2 = *(const uint2*)(t + (size_t)e2.x * 256 + base);
    uint2 v3 = *(const uint2*)(t + (size_t)e3.x * 256 + base);
    a0 += bflo(v0.x) * w0; a1 += bfhi(v0.x) * w0;
    a2 += bflo(v0.y) * w0; a3 += bfhi(v0.y) * w0;
    a0 += bflo(v1.x) * w1; a1 += bfhi(v1.x) * w1;
    a2 += bflo(v1.y) * w1; a3 += bfhi(v1.y) * w1;
    a0 += bflo(v2.x) * w2; a1 += bfhi(v2.x) * w2;
    a2 += bflo(v2.y) * w2; a3 += bfhi(v2.y) * w2;
    a0 += bflo(v3.x) * w3; a1 += bfhi(v3.x) * w3;
    a2 += bflo(v3.y) * w3; a3 += bfhi(v3.y) * w3;
  }
  for (; i < n; ++i) {
    int2 e = srcs2[start + i];
    float w0 = __int_as_float(e.y);
    uint2 v0 = *(const uint2*)(t + (size_t)e.x * 256 + base);
    a0 += bflo(v0.x) * w0; a1 += bfhi(v0.x) * w0;
    a2 += bflo(v0.y) * w0; a3 += bfhi(v0.y) * w0;
  }
  float dj = dinv[j];
  uint2 vj = *(const uint2*)(t + (size_t)j * 256 + base);
  float r0 = (a0 + bflo(vj.x) * dj) * dj + bias[base + 0];
  float r1 = (a1 + bfhi(vj.x) * dj) * dj + bias[base + 1];
  float r2 = (a2 + bflo(vj.y) * dj) * dj + bias[base + 2];
  float r3 = (a3 + bfhi(vj.y) * dj) * dj + bias[base + 3];
  if (RELU) {
    r0 = fmaxf(r0, 0.f); r1 = fmaxf(r1, 0.f);
    r2 = fmaxf(r2, 0.f); r3 = fmaxf(r3, 0.f);
  }
  unsigned int o0 = ((unsigned int)f2bf(r1) << 16) | f2bf(r0);
  unsigned int o1 = ((unsigned int)f2bf(r3) << 16) | f2bf(r2);
  *(uint2*)(out + (size_t)j * 256 + base) = make_uint2(o0, o1);
}

// D=64 variant: bf16 in, bf16 out (feeds final MFMA layer), no relu
__global__ __launch_bounds__(64) void agg64_kernel(
    const US* __restrict__ t, US* __restrict__ out,
    const int* __restrict__ row_ptr, const int* __restrict__ cnt,
    const int2* __restrict__ srcs2, const float* __restrict__ dinv,
    const float* __restrict__ bias) {
  int j = blockIdx.x;
  int lane = threadIdx.x;
  int start = row_ptr[j];
  int n = cnt[j];
  float acc = 0.f;
  int i = 0;
  for (; i + 3 < n; i += 4) {
    int2 e0 = srcs2[start + i + 0];
    int2 e1 = srcs2[start + i + 1];
    int2 e2 = srcs2[start + i + 2];
    int2 e3 = srcs2[start + i + 3];
    acc += bf2f(t[(size_t)e0.x * 64 + lane]) * __int_as_float(e0.y);
    acc += bf2f(t[(size_t)e1.x * 64 + lane]) * __int_as_float(e1.y);
    acc += bf2f(t[(size_t)e2.x * 64 + lane]) * __int_as_float(e2.y);
    acc += bf2f(t[(size_t)e3.x * 64 + lane]) * __int_as_float(e3.y);
  }
  for (; i < n; ++i) {
    int2 e = srcs2[start + i];
    acc += bf2f(t[(size_t)e.x * 64 + lane]) * __int_as_float(e.y);
  }
  float dj = dinv[j];
  float r = (acc + bf2f(t[(size_t)j * 64 + lane]) * dj) * dj + bias[lane];
  out[(size_t)j * 64 + lane] = f2bf(r);
}

// ----------------- final dense: sigmoid(H[N,64] @ W4t^T + b4), MFMA -----------------

__global__ __launch_bounds__(256) void final_mfma_kernel(
    const US* __restrict__ H, const US* __restrict__ W4t,
    const float* __restrict__ b4, float* __restrict__ out, int M) {
  int wv = threadIdx.x >> 6, lane = threadIdx.x & 63;
  int m0 = blockIdx.x * 64 + wv * 16;
  if (m0 >= M) return;
  int lm = lane & 15, lk = lane >> 4;

  floatx4 zero = {0.f, 0.f, 0.f, 0.f};
  floatx4 acc[4] = {zero, zero, zero, zero};
#pragma unroll
  for (int ks = 0; ks < 2; ++ks) {
    short8 af = *(const short8*)&H[(size_t)(m0 + lm) * 64 + ks * 32 + lk * 8];
#pragma unroll
    for (int jt = 0; jt < 4; ++jt) {
      short8 bf = *(const short8*)&W4t[(size_t)(jt * 16 + lm) * 64 + ks * 32 + lk * 8];
      acc[jt] = __builtin_amdgcn_mfma_f32_16x16x32_bf16(af, bf, acc[jt], 0, 0, 0);
    }
  }
#pragma unroll
  for (int jt = 0; jt < 4; ++jt) {
    int col = jt * 16 + lm;
    float bv = b4[col];
#pragma unroll
    for (int r = 0; r < 4; ++r) {
      int m = m0 + lk * 4 + r;
      float v = acc[jt][r] + bv;
      out[(size_t)m * 64 + col] = 1.0f / (1.0f + expf(-v));
    }
  }
}

// ----------------- driver -----------------

extern "C" void kernel_launch(void* const* d_in, const int* in_sizes, int n_in,
                              void* d_out, int out_size, void* d_ws, size_t ws_size,
                              hipStream_t stream) {
  const float* x  = (const float*)d_in[0];
  const int* ei   = (const int*)d_in[1];
  const float* W1 = (const float*)d_in[2];
  const float* b1 = (const float*)d_in[3];
  const float* W2 = (const float*)d_in[4];
  const float* b2 = (const float*)d_in[5];
  const float* W3 = (const float*)d_in[6];
  const float* b3 = (const float*)d_in[7];
  const float* W4 = (const float*)d_in[8];
  const float* b4 = (const float*)d_in[9];
  float* outp = (float*)d_out;

  const int N = N_NODES, E = N_EDGES;
  const int* row = ei;
  const int* col = ei + E;

  // workspace layout (~72 MB)
  US* Ab = (US*)d_ws;                         // [N,256] bf16 ping
  US* Bb = Ab + (size_t)N * 256;              // [N,256] bf16 pong
  US* B64 = Bb + (size_t)N * 256;             // [N,64] (layer-6 GEMM out)
  US* Hfin = B64 + (size_t)N * 64;            // [N,64] (final GEMM in)
  float* dinv = (float*)(Hfin + (size_t)N * 64);
  int* cnt = (int*)(dinv + N);
  int* row_ptr = cnt + N;
  int* fill = row_ptr + N;
  int* bsums = fill + N;                      // [256]
  int2* srcs2 = (int2*)(bsums + 256);         // [E] (src, dinv[src])
  US* Wt1 = (US*)(srcs2 + E);                 // [256,256] bf16 transposed
  US* Wt2 = Wt1 + 256 * 256;
  US* Wt3 = Wt2 + 256 * 256;                  // [64,256]
  US* Wt4 = Wt3 + 64 * 256;                   // [64,64]

  hipMemsetAsync(cnt, 0, N * sizeof(int), stream);
  count_kernel<<<(E + 255) / 256, 256, 0, stream>>>(col, cnt, E);
  int nblk = (N + 255) / 256;
  scan_block_kernel<<<nblk, 256, 0, stream>>>(cnt, row_ptr, bsums, dinv, N);
  scan_top_kernel<<<1, 256, 0, stream>>>(bsums, nblk);
  scan_add_kernel<<<nblk, 256, 0, stream>>>(row_ptr, fill, bsums, N);
  fill_kernel<<<(E + 255) / 256, 256, 0, stream>>>(row, col, fill, srcs2, dinv, E);

  cvt_x_kernel<<<(N * 256 / 4 + 255) / 256, 256, 0, stream>>>(x, Ab, N * 256 / 4);
  cvt_w_all_kernel<<<(151552 + 255) / 256, 256, 0, stream>>>(W1, W2, W3, W4, Wt1, Wt2, Wt3, Wt4);

  int gm64 = (N + 63) / 64;     // 782
  int gm128 = (N + 127) / 128;  // 391

  gemm256_kernel<<<gm64, 256, 0, stream>>>(Ab, Wt1, Bb, N);
  agg256_kernel<true><<<N, 64, 0, stream>>>(Bb, Ab, row_ptr, cnt, srcs2, dinv, b1);
  for (int l = 0; l < 4; ++l) {
    gemm256_kernel<<<gm64, 256, 0, stream>>>(Ab, Wt2, Bb, N);
    agg256_kernel<true><<<N, 64, 0, stream>>>(Bb, Ab, row_ptr, cnt, srcs2, dinv, b2);
  }
  gemm64_kernel<<<gm128, 256, 0, stream>>>(Ab, Wt3, B64, N);
  agg64_kernel<<<N, 64, 0, stream>>>(B64, Hfin, row_ptr, cnt, srcs2, dinv, b3);
  final_mfma_kernel<<<(N + 63) / 64, 256, 0, stream>>>(Hfin, Wt4, b4, outp, N);
}